// Round 10
// baseline (285.839 us; speedup 1.0000x reference)
//
#include <hip/hip_runtime.h>
#include <cstddef>

// RNN: h_t = tanh(x_t @ W_ih^T + b_ih + h_{t-1} @ W_hh^T + b_hh), return h_T.
// B=4096, T=512, IN=15, H=20.
//
// R8 post-mortem: "off-chain-first" rotation + SALU addressing + unroll16
// REGRESSED 83.4->119us (pure stall: all utilizations -42%, bytes flat).
// With 1 wave/SIMD program order = issue order: the rotation moved a
// vmcnt-waited XR read + 2 MFMA issues INTO the Bh->recMFMA gap, and the
// reorder/unroll shifted compiler vmcnt placement conservative. Reverted.
//
// R9: two independent chains per wave (32 batches = 2 x 16), half-phase
// interleave. Per-step exposed latency (~240cy: MFMA result latency + exp/
// rcp chain) is hidden behind the OTHER chain's ~190cy of issue:
//   round: A.tanh(r-1); A.mfma(r); A.x | B.tanh(r-1); B.mfma(r); B.x
// Each chain's mfma->tanh window spans the other chain's block. Round ~
// max(2*issue, issue+lat) ~ 300-345cy for one step of BOTH chains (vs 391).
// Wall = 512 * round (128 waves on 128 CUs; wall is per-wave serial).
// Per-chain structure = R7 verbatim: pi-packed K slots (B slot 8G+i holds
// u[5G+i], i<5; sigma_P(m)=5(m>>2)+(m&3), sigma_Q=5(m>>2)+4), u-carry
// (u=1/(1+2^z), -2 folded into A, +K2*rowsum(Whh) into bias, h=1-2u),
// x via per-lane global_load_dwordx4 register pipeline (depth 4/chain,
// consumed 4 rounds ~ 1280cy after issue), cx MFMAs off-chain 1 step ahead,
// no LDS. Weights pre-scaled by K2=2*log2(e).
// Loop runs 512 rounds; round 512's mfma(512) is discarded waste (~0.2%)
// to keep trip count unroll-8-aligned with static XR indices.

typedef float f4 __attribute__((ext_vector_type(4)));
typedef float g4 __attribute__((ext_vector_type(4), aligned(4)));
typedef _Float16 h2 __attribute__((ext_vector_type(2)));
typedef _Float16 v4h __attribute__((ext_vector_type(4)));
typedef _Float16 v8h __attribute__((ext_vector_type(8)));
typedef __fp16 p2 __attribute__((ext_vector_type(2)));

#define TT 512
#define IN 15
#define HD 20
#define NB 32  // 2 chains x 16 batches per wave

__device__ __forceinline__ float fexp2(float x) {
#if __has_builtin(__builtin_amdgcn_exp2f)
  return __builtin_amdgcn_exp2f(x);  // native v_exp_f32
#else
  return exp2f(x);
#endif
}
__device__ __forceinline__ h2 pk2(float a, float b) {
  p2 r = __builtin_amdgcn_cvt_pkrtz(a, b);
  return __builtin_bit_cast(h2, r);
}
__device__ __forceinline__ v4h cat4(h2 a, h2 b) {
  return __builtin_shufflevector(a, b, 0, 1, 2, 3);
}
__device__ __forceinline__ v8h cat8(v4h a, v4h b) {
  return __builtin_shufflevector(a, b, 0, 1, 2, 3, 4, 5, 6, 7);
}

__global__ __launch_bounds__(64) void rnn_mfma(
    const float* __restrict__ feature, const float* __restrict__ W_ih,
    const float* __restrict__ W_hh, const float* __restrict__ b_ih,
    const float* __restrict__ b_hh, float* __restrict__ out, int B) {
  const int l = threadIdx.x;   // 0..63
  const int G = l >> 4;        // k-group 0..3
  const int mf = l & 15;       // A fragment row / B,D batch column
  const int b0 = blockIdx.x * NB;

  const float K2 = 2.8853900817779268f;  // 2*log2(e)

  // --- row assignments (pi-packing), shared by both chains -----------
  const int jP = 5 * (mf >> 2) + (mf & 3);  // sigma_P(mf), < 20
  const int jQ = 5 * (mf >> 2) + 4;         // sigma_Q(mf), < 20

  v8h AhhP, AhhQ;  // A[m][k=8G+i] = -2*K2*Whh[sigma(m)][5G+i], i<5
#pragma unroll
  for (int i = 0; i < 8; ++i) {
    const int k = 5 * G + i;
    const float wP = (i < 5) ? -2.f * K2 * W_hh[jP * HD + k] : 0.f;
    const float wQ = (i < 5) ? -2.f * K2 * W_hh[jQ * HD + k] : 0.f;
    AhhP[i] = (_Float16)wP;
    AhhQ[i] = (_Float16)wQ;
  }
  // x-projection A (16x16x16). G=3 shifts to k0=11 (avoids 4B OOB at the
  // last feature row); duplicate k=11 zeroed in G=2.
  const int k0 = (G < 3) ? 4 * G : 11;
  v4h AihP, AihQ;
#pragma unroll
  for (int i = 0; i < 4; ++i) {
    const int k = k0 + i;
    const bool dup = (G == 2 && i == 3);
    AihP[i] = (_Float16)((k < IN && !dup) ? K2 * W_ih[jP * IN + k] : 0.f);
    AihQ[i] = (_Float16)((k < IN && !dup) ? K2 * W_ih[jQ * IN + k] : 0.f);
  }
  // bias C fragments incl. +K2*rowsum(Whh) from the h = 1-2u fold
  f4 biasP, biasQ;
#pragma unroll
  for (int r = 0; r < 4; ++r) {
    const int jp = 5 * G + r, jq = 5 * G + 4;
    float rsP = 0.f, rsQ = 0.f;
#pragma unroll
    for (int k = 0; k < HD; ++k) {
      rsP += W_hh[jp * HD + k];
      rsQ += W_hh[jq * HD + k];
    }
    biasP[r] = K2 * (b_ih[jp] + b_hh[jp] + rsP);
    biasQ[r] = K2 * (b_ih[jq] + b_hh[jq] + rsQ);
  }

  // --- per-lane x sources (R7-style VGPR addressing; NOT SALU-ized) ---
  const int bA = min(b0 + mf, B - 1);
  const int bB = min(b0 + 16 + mf, B - 1);
  const float* xbA = feature + (size_t)bA * TT * IN + k0;
  const float* xbB = feature + (size_t)bB * TT * IN + k0;
  auto ldA = [&](int t) -> g4 { return *(const g4*)(xbA + (size_t)t * IN); };
  auto ldB = [&](int t) -> g4 { return *(const g4*)(xbB + (size_t)t * IN); };

  // depth-4 register pipelines, slot s = t & 3; initially x(2..5).
  g4 XRA[4], XRB[4];
#pragma unroll
  for (int t = 2; t <= 5; ++t) {
    XRA[t & 3] = ldA(t);
    XRB[t & 3] = ldB(t);
  }

  // prologue: cx(0) -> rec mfma(0); then cx(1) for round 1.
  g4 xa0 = ldA(0), xb0 = ldB(0);
  v4h XA = cat4(pk2(xa0.x, xa0.y), pk2(xa0.z, xa0.w));
  v4h XB = cat4(pk2(xb0.x, xb0.y), pk2(xb0.z, xb0.w));
  f4 cxAP = __builtin_amdgcn_mfma_f32_16x16x16f16(AihP, XA, biasP, 0, 0, 0);
  f4 cxAQ = __builtin_amdgcn_mfma_f32_16x16x16f16(AihQ, XA, biasQ, 0, 0, 0);
  f4 cxBP = __builtin_amdgcn_mfma_f32_16x16x16f16(AihP, XB, biasP, 0, 0, 0);
  f4 cxBQ = __builtin_amdgcn_mfma_f32_16x16x16f16(AihQ, XB, biasQ, 0, 0, 0);

  v8h BhA, BhB;  // u-carry; h0 = 0 <=> u0 = 0.5 in live slots
#pragma unroll
  for (int i = 0; i < 8; ++i) {
    BhA[i] = (_Float16)((i < 5) ? 0.5f : 0.f);
    BhB[i] = (_Float16)((i < 5) ? 0.5f : 0.f);
  }

  f4 aAP = __builtin_amdgcn_mfma_f32_16x16x32_f16(AhhP, BhA, cxAP, 0, 0, 0);
  f4 aAQ = __builtin_amdgcn_mfma_f32_16x16x32_f16(AhhQ, BhA, cxAQ, 0, 0, 0);
  f4 aBP = __builtin_amdgcn_mfma_f32_16x16x32_f16(AhhP, BhB, cxBP, 0, 0, 0);
  f4 aBQ = __builtin_amdgcn_mfma_f32_16x16x32_f16(AhhQ, BhB, cxBQ, 0, 0, 0);

  g4 xa1 = ldA(1), xb1 = ldB(1);
  XA = cat4(pk2(xa1.x, xa1.y), pk2(xa1.z, xa1.w));
  XB = cat4(pk2(xb1.x, xb1.y), pk2(xb1.z, xb1.w));
  cxAP = __builtin_amdgcn_mfma_f32_16x16x16f16(AihP, XA, biasP, 0, 0, 0);
  cxAQ = __builtin_amdgcn_mfma_f32_16x16x16f16(AihQ, XA, biasQ, 0, 0, 0);
  cxBP = __builtin_amdgcn_mfma_f32_16x16x16f16(AihP, XB, biasP, 0, 0, 0);
  cxBQ = __builtin_amdgcn_mfma_f32_16x16x16f16(AihQ, XB, biasQ, 0, 0, 0);

  float uPA[4], uPB[4], uQA = 0.5f, uQB = 0.5f;
  const h2 zero2 = {(_Float16)0.f, (_Float16)0.f};

  // round r: {A,B}.tanh(r-1) -> Bh -> rec mfma(r) -> x machinery(r+1).
  // Each chain's mfma->tanh window spans the other chain's full block.
#pragma unroll 8
  for (int r = 1; r <= TT; ++r) {
    // ---- chain A ----
    uQA = __builtin_amdgcn_rcpf(1.f + fexp2(aAQ[0]));
#pragma unroll
    for (int q = 0; q < 4; ++q)
      uPA[q] = __builtin_amdgcn_rcpf(1.f + fexp2(aAP[q]));
    BhA = cat8(cat4(pk2(uPA[0], uPA[1]), pk2(uPA[2], uPA[3])),
               cat4(pk2(uQA, 0.f), zero2));
    aAP = __builtin_amdgcn_mfma_f32_16x16x32_f16(AhhP, BhA, cxAP, 0, 0, 0);
    aAQ = __builtin_amdgcn_mfma_f32_16x16x32_f16(AhhQ, BhA, cxAQ, 0, 0, 0);
    {
      const int s = (r + 1) & 3;  // x(r+1), loaded 4 rounds ago
      g4 xr = XRA[s];
      v4h Xn = cat4(pk2(xr.x, xr.y), pk2(xr.z, xr.w));
      cxAP = __builtin_amdgcn_mfma_f32_16x16x16f16(AihP, Xn, biasP, 0, 0, 0);
      cxAQ = __builtin_amdgcn_mfma_f32_16x16x16f16(AihQ, Xn, biasQ, 0, 0, 0);
      const int tn = r + 5;
      XRA[s] = ldA(tn < TT ? tn : TT - 1);  // clamped tail: harmless
    }
    // ---- chain B ----
    uQB = __builtin_amdgcn_rcpf(1.f + fexp2(aBQ[0]));
#pragma unroll
    for (int q = 0; q < 4; ++q)
      uPB[q] = __builtin_amdgcn_rcpf(1.f + fexp2(aBP[q]));
    BhB = cat8(cat4(pk2(uPB[0], uPB[1]), pk2(uPB[2], uPB[3])),
               cat4(pk2(uQB, 0.f), zero2));
    aBP = __builtin_amdgcn_mfma_f32_16x16x32_f16(AhhP, BhB, cxBP, 0, 0, 0);
    aBQ = __builtin_amdgcn_mfma_f32_16x16x32_f16(AhhQ, BhB, cxBQ, 0, 0, 0);
    {
      const int s = (r + 1) & 3;
      g4 xr = XRB[s];
      v4h Xn = cat4(pk2(xr.x, xr.y), pk2(xr.z, xr.w));
      cxBP = __builtin_amdgcn_mfma_f32_16x16x16f16(AihP, Xn, biasP, 0, 0, 0);
      cxBQ = __builtin_amdgcn_mfma_f32_16x16x16f16(AihQ, Xn, biasQ, 0, 0, 0);
      const int tn = r + 5;
      XRB[s] = ldB(tn < TT ? tn : TT - 1);
    }
  }
  // rounds 1..512 computed tanh(0..511); round 512's mfma(512) is waste.

  // epilogue: h_T = 1 - 2u. Chain A -> batch b0+mf, chain B -> b0+16+mf;
  // P r -> j=5G+r, Q -> j=5G+4 (all < 20 by construction).
  const int batchA = b0 + mf;
  if (batchA < B) {
    float* orow = out + (size_t)batchA * HD;
#pragma unroll
    for (int r = 0; r < 4; ++r) orow[5 * G + r] = 1.f - 2.f * uPA[r];
    orow[5 * G + 4] = 1.f - 2.f * uQA;
  }
  const int batchB = b0 + 16 + mf;
  if (batchB < B) {
    float* orow = out + (size_t)batchB * HD;
#pragma unroll
    for (int r = 0; r < 4; ++r) orow[5 * G + r] = 1.f - 2.f * uPB[r];
    orow[5 * G + 4] = 1.f - 2.f * uQB;
  }
}

extern "C" void kernel_launch(void* const* d_in, const int* in_sizes, int n_in,
                              void* d_out, int out_size, void* d_ws, size_t ws_size,
                              hipStream_t stream) {
  const float* feature = (const float*)d_in[0];
  const float* W_ih    = (const float*)d_in[1];
  const float* W_hh    = (const float*)d_in[2];
  const float* b_ih    = (const float*)d_in[3];
  const float* b_hh    = (const float*)d_in[4];
  float* out = (float*)d_out;
  const int B = in_sizes[0] / (TT * IN);   // 4096
  const int grid = (B + NB - 1) / NB;      // 32 batches (2 chains) per wave
  rnn_mfma<<<grid, 64, 0, stream>>>(feature, W_ih, W_hh, b_ih, b_hh, out, B);
}

// Round 11
// 201.480 us; speedup vs baseline: 1.4187x; 1.4187x over previous
//
#include <hip/hip_runtime.h>
#include <cstddef>
#include <cstdint>

// RNN: h_t = tanh(x_t @ W_ih^T + b_ih + h_{t-1} @ W_hh^T + b_hh), return h_T.
// B=4096, T=512, IN=15, H=20.
//
// R9 post-mortem: 2-chain interleave gave ~0 overlap (707 cyc/round vs
// 2x391): each chain's block paid its own ~300cy stall even with the other
// chain's independent work right behind it -> the stall is a WAVE-BLOCKING
// s_waitcnt, not fillable latency. Consistent across R5/R7/R8/R9: compiler
// emits conservative vmcnt(~0) before each step's XR read (loses tracking
// through the rotating pipeline), waiting on a ~1-step-old cold HBM load.
//
// R10: R7 structure verbatim (83.4us baseline) + x loads via inline-asm
// global_load_dwordx4 (compiler can't see them -> emits no waits) and an
// EXPLICIT s_waitcnt vmcnt(7) + sched_barrier(0) before consuming the slot
// loaded 8 steps (~3100cy) ago -> the wait is always satisfied. T4 counted
// vmcnt (m218) on a register pipeline; rule #18 fence stops hoisting.
//
// Carried (verified R7): pi-packed K slots (B slot 8G+i holds u[5G+i], i<5;
// sigma_P(m)=5(m>>2)+(m&3), sigma_Q=5(m>>2)+4), u-carry u=1/(1+2^z) with
// -2 folded into A and +K2*rowsum(Whh) into bias, h=1-2u epilogue, cx MFMAs
// off-chain one step ahead, no LDS, weights pre-scaled by K2=2*log2(e).

typedef float f4 __attribute__((ext_vector_type(4)));
typedef float g4 __attribute__((ext_vector_type(4), aligned(4)));
typedef _Float16 h2 __attribute__((ext_vector_type(2)));
typedef _Float16 v4h __attribute__((ext_vector_type(4)));
typedef _Float16 v8h __attribute__((ext_vector_type(8)));
typedef __fp16 p2 __attribute__((ext_vector_type(2)));

#define TT 512
#define IN 15
#define HD 20
#define NB 16  // batches per wave

__device__ __forceinline__ float fexp2(float x) {
#if __has_builtin(__builtin_amdgcn_exp2f)
  return __builtin_amdgcn_exp2f(x);  // native v_exp_f32
#else
  return exp2f(x);
#endif
}
__device__ __forceinline__ h2 pk2(float a, float b) {
  p2 r = __builtin_amdgcn_cvt_pkrtz(a, b);
  return __builtin_bit_cast(h2, r);
}
__device__ __forceinline__ v4h cat4(h2 a, h2 b) {
  return __builtin_shufflevector(a, b, 0, 1, 2, 3);
}
__device__ __forceinline__ v8h cat8(v4h a, v4h b) {
  return __builtin_shufflevector(a, b, 0, 1, 2, 3, 4, 5, 6, 7);
}

// x load the compiler cannot see: no compiler-emitted vmcnt for its result.
__device__ __forceinline__ g4 ld_x_asm(const float* p) {
  g4 r;
  asm volatile("global_load_dwordx4 %0, %1, off"
               : "=v"(r)
               : "v"(p));
  return r;
}

__global__ __launch_bounds__(64) void rnn_mfma(
    const float* __restrict__ feature, const float* __restrict__ W_ih,
    const float* __restrict__ W_hh, const float* __restrict__ b_ih,
    const float* __restrict__ b_hh, float* __restrict__ out, int B) {
  const int l = threadIdx.x;   // 0..63
  const int G = l >> 4;        // k-group 0..3
  const int mf = l & 15;       // A fragment row / B,D batch column
  const int b0 = blockIdx.x * NB;

  const float K2 = 2.8853900817779268f;  // 2*log2(e)

  // --- row assignments (pi-packing) ---------------------------------
  const int jP = 5 * (mf >> 2) + (mf & 3);  // sigma_P(mf), < 20
  const int jQ = 5 * (mf >> 2) + 4;         // sigma_Q(mf), < 20

  v8h AhhP, AhhQ;  // A[m][k=8G+i] = -2*K2*Whh[sigma(m)][5G+i], i<5
#pragma unroll
  for (int i = 0; i < 8; ++i) {
    const int k = 5 * G + i;
    const float wP = (i < 5) ? -2.f * K2 * W_hh[jP * HD + k] : 0.f;
    const float wQ = (i < 5) ? -2.f * K2 * W_hh[jQ * HD + k] : 0.f;
    AhhP[i] = (_Float16)wP;
    AhhQ[i] = (_Float16)wQ;
  }
  // x-projection A (16x16x16). G=3 shifts to k0=11 (avoids 4B OOB at the
  // last feature row); duplicate k=11 zeroed in G=2.
  const int k0 = (G < 3) ? 4 * G : 11;
  v4h AihP, AihQ;
#pragma unroll
  for (int i = 0; i < 4; ++i) {
    const int k = k0 + i;
    const bool dup = (G == 2 && i == 3);
    AihP[i] = (_Float16)((k < IN && !dup) ? K2 * W_ih[jP * IN + k] : 0.f);
    AihQ[i] = (_Float16)((k < IN && !dup) ? K2 * W_ih[jQ * IN + k] : 0.f);
  }
  // bias C fragments incl. +K2*rowsum(Whh) from the h = 1-2u fold
  f4 biasP, biasQ;
#pragma unroll
  for (int r = 0; r < 4; ++r) {
    const int jp = 5 * G + r, jq = 5 * G + 4;
    float rsP = 0.f, rsQ = 0.f;
#pragma unroll
    for (int k = 0; k < HD; ++k) {
      rsP += W_hh[jp * HD + k];
      rsQ += W_hh[jq * HD + k];
    }
    biasP[r] = K2 * (b_ih[jp] + b_hh[jp] + rsP);
    biasQ[r] = K2 * (b_ih[jq] + b_hh[jq] + rsQ);
  }

  // --- per-lane x fragment source: 16B at feature[b][t][k0] ----------
  const int b = min(b0 + mf, B - 1);
  const float* xbase = feature + (size_t)b * TT * IN + k0;

  // depth-8 register pipeline (asm loads; static indices under unroll).
  g4 XR[8];
#pragma unroll
  for (int s = 1; s <= 8; ++s) XR[s & 7] = ld_x_asm(xbase + (size_t)s * IN);

  // prologue: cx(0). Plain compiler load for x(0): its conservative wait
  // drains the prologue asm loads once -- negligible one-time cost.
  g4 x0 = *(const g4*)(xbase);
  v4h X0 = cat4(pk2(x0.x, x0.y), pk2(x0.z, x0.w));
  f4 cxPc = __builtin_amdgcn_mfma_f32_16x16x16f16(AihP, X0, biasP, 0, 0, 0);
  f4 cxQc = __builtin_amdgcn_mfma_f32_16x16x16f16(AihQ, X0, biasQ, 0, 0, 0);

  // B-fragment carries u; h0 = 0 <=> u0 = 0.5 in live slots (i<5).
  v8h Bh;
#pragma unroll
  for (int i = 0; i < 8; ++i) Bh[i] = (_Float16)((i < 5) ? 0.5f : 0.f);

  float uP[4], uQ0 = 0.5f;  // last u values -> epilogue h = 1-2u
#pragma unroll
  for (int r = 0; r < 4; ++r) uP[r] = 0.5f;

  const h2 zero2 = {(_Float16)0.f, (_Float16)0.f};

  for (int t = 0; t < TT; t += 8) {
#pragma unroll
    for (int u = 0; u < 8; ++u) {
      // --- recurrence chain: mfma -> u=rcp(1+2^z) -> pack -> mfma ---
      f4 aP = __builtin_amdgcn_mfma_f32_16x16x32_f16(AhhP, Bh, cxPc, 0, 0, 0);
      f4 aQ = __builtin_amdgcn_mfma_f32_16x16x32_f16(AhhQ, Bh, cxQc, 0, 0, 0);
      // --- counted wait: XR[s] was loaded 8 steps (~3100cy) ago; with 8
      // outstanding, vmcnt(7) admits the 7 newer loads and is satisfied.
      const int s = (u + 1) & 7;
      asm volatile("s_waitcnt vmcnt(7)");
      __builtin_amdgcn_sched_barrier(0);  // no consumer hoists past the wait
      g4 xr = XR[s];  // x(t+u+1)
      v4h Xn = cat4(pk2(xr.x, xr.y), pk2(xr.z, xr.w));
      cxPc = __builtin_amdgcn_mfma_f32_16x16x16f16(AihP, Xn, biasP, 0, 0, 0);
      cxQc = __builtin_amdgcn_mfma_f32_16x16x16f16(AihQ, Xn, biasQ, 0, 0, 0);
      // refill slot with x(t+u+9) (clamped tail reloads are harmless)
      const int tn = t + u + 9;
      XR[s] = ld_x_asm(xbase + (size_t)(tn < TT ? tn : TT - 1) * IN);
      // u = 1/(1+2^z): 5 live elements (pi-packing)
#pragma unroll
      for (int r = 0; r < 4; ++r)
        uP[r] = __builtin_amdgcn_rcpf(1.f + fexp2(aP[r]));
      uQ0 = __builtin_amdgcn_rcpf(1.f + fexp2(aQ[0]));
      Bh = cat8(cat4(pk2(uP[0], uP[1]), pk2(uP[2], uP[3])),
                cat4(pk2(uQ0, 0.f), zero2));
    }
  }

  // epilogue: h_T = 1 - 2u. Lane (G,mf): P r -> j=5G+r, Q -> j=5G+4,
  // batch = b0 + mf. All j < 20 by construction.
  const int batch = b0 + mf;
  if (batch < B) {
    float* orow = out + (size_t)batch * HD;
#pragma unroll
    for (int r = 0; r < 4; ++r) orow[5 * G + r] = 1.f - 2.f * uP[r];
    orow[5 * G + 4] = 1.f - 2.f * uQ0;
  }
}

extern "C" void kernel_launch(void* const* d_in, const int* in_sizes, int n_in,
                              void* d_out, int out_size, void* d_ws, size_t ws_size,
                              hipStream_t stream) {
  const float* feature = (const float*)d_in[0];
  const float* W_ih    = (const float*)d_in[1];
  const float* W_hh    = (const float*)d_in[2];
  const float* b_ih    = (const float*)d_in[3];
  const float* b_hh    = (const float*)d_in[4];
  float* out = (float*)d_out;
  const int B = in_sizes[0] / (TT * IN);   // 4096
  const int grid = (B + NB - 1) / NB;      // 16 batches per 64-thread wave
  rnn_mfma<<<grid, 64, 0, stream>>>(feature, W_ih, W_hh, b_ih, b_hh, out, B);
}